// Round 2
// baseline (671.055 us; speedup 1.0000x reference)
//
#include <hip/hip_runtime.h>

#define LATENT 128
#define HIDDEN 256
#define OUTD   128
#define TT     100
#define DECH   64
#define ROWS   8      // batch rows per WG -> 512 WGs -> 2 WGs/CU (two barrier domains)
#define WGSZ   256    // 4 waves

typedef _Float16 f16x8 __attribute__((ext_vector_type(8)));
typedef float    f32x4 __attribute__((ext_vector_type(4)));

#define MFMA16(a,b,c) __builtin_amdgcn_mfma_f32_16x16x32_f16((a),(b),(c),0,0,0)

__device__ __forceinline__ float tanh_fast(float x){
    float e = __expf(2.f*x);                         // e^{2x}
    return 1.f - 2.f*__builtin_amdgcn_rcpf(e + 1.f); // exact limits at +-inf
}

// XOR-swizzled LDS helpers (16B-granule swizzle keeps b128 reads contiguous & conflict-free)
__device__ __forceinline__ f16x8 lds_rd8(const _Float16* b, int sB, int row, int colE){
    int off = row*sB + colE*2; off ^= (row&7)<<4;
    return *(const f16x8*)((const char*)b + off);
}
__device__ __forceinline__ void lds_wr1(_Float16* b, int sB, int row, int colE, float v){
    int off = row*sB + colE*2; off ^= (row&7)<<4;
    *(_Float16*)((char*)b + off) = (_Float16)v;
}

// one-time gather of a B fragment from row-major fp32 W[K][N]:
// lane layout B[k0 + 8*(lane>>4) + i][n]
__device__ __forceinline__ f16x8 gbl_bfrag(const float* W, int ldN, int k0, int n){
    f16x8 f;
#pragma unroll
    for(int i=0;i<8;++i) f[i] = (_Float16)W[(size_t)(k0+i)*ldN + n];
    return f;
}

__global__ __launch_bounds__(WGSZ, 2) void ode_decoder_kernel(
    const float* __restrict__ z0, const float* __restrict__ times,
    const float* __restrict__ W1, const float* __restrict__ b1,
    const float* __restrict__ W2, const float* __restrict__ b2,
    const float* __restrict__ dW1, const float* __restrict__ db1,
    const float* __restrict__ dW2, const float* __restrict__ db2,
    const float* __restrict__ dW3, const float* __restrict__ db3,
    float* __restrict__ out)
{
    __shared__ _Float16 z_lds [16*LATENT] __attribute__((aligned(16)));
    __shared__ _Float16 h_lds [16*HIDDEN] __attribute__((aligned(16)));
    __shared__ _Float16 h1_lds[16*DECH]   __attribute__((aligned(16)));
    __shared__ _Float16 h2_lds[16*DECH]   __attribute__((aligned(16)));
    __shared__ _Float16 dfrag [10*WGSZ*8] __attribute__((aligned(16)));  // decoder B-frag cache

    const int tid  = threadIdx.x;
    const int wv   = tid >> 6;      // 0..3
    const int lane = tid & 63;
    const int lr   = lane & 15;
    const int lg   = lane >> 4;     // 0..3
    const int row0 = 4*lg;          // D-frag row base; valid rows are 0..7 (lg<2)
    const bool act = (lg < 2);
    const int gRow0 = blockIdx.x * ROWS;

    // zero activation LDS once: rows 8..15 stay zero forever (M=16 tiles, 8 valid rows)
    for(int i=tid;i<16*LATENT;i+=WGSZ) z_lds[i]=(_Float16)0.f;
    for(int i=tid;i<16*HIDDEN;i+=WGSZ) h_lds[i]=(_Float16)0.f;
    for(int i=tid;i<16*DECH;i+=WGSZ){ h1_lds[i]=(_Float16)0.f; h2_lds[i]=(_Float16)0.f; }
    __syncthreads();

    // ---------- ODE weights pinned in VGPRs ----------
    // GEMM1: wave owns N-cols [64wv, 64wv+64) as 4 n-tiles
    f16x8 w1f[4][4];
#pragma unroll
    for(int t=0;t<4;++t)
#pragma unroll
        for(int q=0;q<4;++q)
            w1f[t][q] = gbl_bfrag(W1, HIDDEN, 32*q+8*lg, 64*wv+16*t+lr);
    // GEMM2: wave owns N-cols [32wv, 32wv+32) as 2 n-tiles
    f16x8 w2f[2][8];
#pragma unroll
    for(int u=0;u<2;++u)
#pragma unroll
        for(int q=0;q<8;++q)
            w2f[u][q] = gbl_bfrag(W2, LATENT, 32*q+8*lg, 32*wv+16*u+lr);

    // ---------- decoder B-frags -> LDS frag cache (per-lane 16B blobs, conflict-free) ----------
    {
        const int dcol = 16*wv + lr;
#pragma unroll
        for(int q=0;q<4;++q)
            *(f16x8*)(dfrag + (size_t)(q*WGSZ + tid)*8)       = gbl_bfrag(dW1, DECH, 32*q+8*lg, dcol);
#pragma unroll
        for(int q=0;q<2;++q)
            *(f16x8*)(dfrag + (size_t)((4+q)*WGSZ + tid)*8)   = gbl_bfrag(dW2, DECH, 32*q+8*lg, dcol);
#pragma unroll
        for(int u=0;u<2;++u)
#pragma unroll
            for(int q=0;q<2;++q)
                *(f16x8*)(dfrag + (size_t)((6+2*u+q)*WGSZ + tid)*8) = gbl_bfrag(dW3, OUTD, 32*q+8*lg, 32*wv+16*u+lr);
    }
    auto DF = [&](int f){ return *(const f16x8*)(dfrag + (size_t)(f*WGSZ + tid)*8); };

    float b1v[4], b2v[2], db3v[2];
#pragma unroll
    for(int t=0;t<4;++t) b1v[t] = b1[64*wv+16*t+lr];
#pragma unroll
    for(int u=0;u<2;++u){ b2v[u] = b2[32*wv+16*u+lr]; db3v[u] = db3[32*wv+16*u+lr]; }
    const float db1v = db1[16*wv+lr], db2v = db2[16*wv+lr];

    // ---------- state: lane (lg<2) owns z[row0+r][32wv+16u+lr] ----------
    f32x4 z[2], acc[2];
#pragma unroll
    for(int u=0;u<2;++u)
#pragma unroll
        for(int r=0;r<4;++r){
            float v = 0.f;
            if(act) v = z0[(size_t)(gRow0+row0+r)*LATENT + 32*wv+16*u+lr];
            z[u][r] = v;
        }
    if(act){
#pragma unroll
        for(int u=0;u<2;++u)
#pragma unroll
            for(int r=0;r<4;++r) lds_wr1(z_lds, LATENT*2, row0+r, 32*wv+16*u+lr, z[u][r]);
    }
    __syncthreads();

#pragma unroll 1
    for(int k=0;k<TT-1;++k){
        const float hs = times[k+1]-times[k];
#pragma unroll
        for(int s=0;s<4;++s){
            // ================= G1 segment =================
            f16x8 az[4];
#pragma unroll
            for(int q=0;q<4;++q) az[q] = lds_rd8(z_lds, LATENT*2, lr, 32*q+8*lg);
            {
                f32x4 c[4];
#pragma unroll
                for(int t=0;t<4;++t) c[t] = (f32x4){b1v[t],b1v[t],b1v[t],b1v[t]};
#pragma unroll
                for(int q=0;q<4;++q)
#pragma unroll
                    for(int t=0;t<4;++t) c[t] = MFMA16(az[q], w1f[t][q], c[t]);
                if(act){
#pragma unroll
                    for(int t=0;t<4;++t)
#pragma unroll
                        for(int r=0;r<4;++r)
                            lds_wr1(h_lds, HIDDEN*2, row0+r, 64*wv+16*t+lr, tanh_fast(c[t][r]));
                }
            }
            if(s==0){ // dGEMM1: relu(z_k @ dW1 + db1) -> h1 (reuses az)
                f32x4 c = {db1v,db1v,db1v,db1v};
#pragma unroll
                for(int q=0;q<4;++q) c = MFMA16(az[q], DF(q), c);
                if(act){
#pragma unroll
                    for(int r=0;r<4;++r) lds_wr1(h1_lds, DECH*2, row0+r, 16*wv+lr, fmaxf(c[r],0.f));
                }
            }
            if(s==1){ // dGEMM3: h2 @ dW3 + db3 -> out[:,k,:]
                f16x8 a2[2];
#pragma unroll
                for(int q=0;q<2;++q) a2[q] = lds_rd8(h2_lds, DECH*2, lr, 32*q+8*lg);
#pragma unroll
                for(int u=0;u<2;++u){
                    f32x4 c = {db3v[u],db3v[u],db3v[u],db3v[u]};
#pragma unroll
                    for(int q=0;q<2;++q) c = MFMA16(a2[q], DF(6+2*u+q), c);
                    if(act){
#pragma unroll
                        for(int r=0;r<4;++r)
                            out[(size_t)(gRow0+row0+r)*TT*OUTD + (size_t)k*OUTD + 32*wv+16*u+lr] = c[r];
                    }
                }
            }
            __syncthreads();
            // ================= G2 segment =================
            f32x4 kk[2];
            {
                f16x8 ah[8];
#pragma unroll
                for(int q=0;q<8;++q) ah[q] = lds_rd8(h_lds, HIDDEN*2, lr, 32*q+8*lg);
#pragma unroll
                for(int u=0;u<2;++u){
                    f32x4 ca = (f32x4){b2v[u],b2v[u],b2v[u],b2v[u]};
                    f32x4 cb = (f32x4){0.f,0.f,0.f,0.f};
#pragma unroll
                    for(int q=0;q<4;++q) ca = MFMA16(ah[q],   w2f[u][q],   ca);
#pragma unroll
                    for(int q=0;q<4;++q) cb = MFMA16(ah[4+q], w2f[u][4+q], cb);
                    kk[u] = ca + cb;   // split dep chain 8 -> 2x4
                }
            }
            if(s==0){ // dGEMM2: relu(h1 @ dW2 + db2) -> h2
                f16x8 a1[2];
#pragma unroll
                for(int q=0;q<2;++q) a1[q] = lds_rd8(h1_lds, DECH*2, lr, 32*q+8*lg);
                f32x4 c = {db2v,db2v,db2v,db2v};
#pragma unroll
                for(int q=0;q<2;++q) c = MFMA16(a1[q], DF(4+q), c);
                if(act){
#pragma unroll
                    for(int r=0;r<4;++r) lds_wr1(h2_lds, DECH*2, row0+r, 16*wv+lr, fmaxf(c[r],0.f));
                }
            }
            // RK4 combine (fp32 in registers) + write next z-stage
            f32x4 zs[2];
#pragma unroll
            for(int u=0;u<2;++u){
                if(s==0){ acc[u] = z[u] + kk[u]*(hs*(1.f/6.f)); zs[u] = z[u] + kk[u]*(hs*0.5f); }
                else if(s==1){ acc[u] += kk[u]*(hs*(1.f/3.f)); zs[u] = z[u] + kk[u]*(hs*0.5f); }
                else if(s==2){ acc[u] += kk[u]*(hs*(1.f/3.f)); zs[u] = z[u] + kk[u]*hs; }
                else { z[u] = acc[u] + kk[u]*(hs*(1.f/6.f)); zs[u] = z[u]; }
            }
            if(act){
#pragma unroll
                for(int u=0;u<2;++u)
#pragma unroll
                    for(int r=0;r<4;++r) lds_wr1(z_lds, LATENT*2, row0+r, 32*wv+16*u+lr, zs[u][r]);
            }
            __syncthreads();
        }
    }

    // ---------- final decode of z_{TT-1} ----------
    {
        f16x8 az[4];
#pragma unroll
        for(int q=0;q<4;++q) az[q] = lds_rd8(z_lds, LATENT*2, lr, 32*q+8*lg);
        f32x4 c = {db1v,db1v,db1v,db1v};
#pragma unroll
        for(int q=0;q<4;++q) c = MFMA16(az[q], DF(q), c);
        if(act){
#pragma unroll
            for(int r=0;r<4;++r) lds_wr1(h1_lds, DECH*2, row0+r, 16*wv+lr, fmaxf(c[r],0.f));
        }
        __syncthreads();
        f16x8 a1[2];
#pragma unroll
        for(int q=0;q<2;++q) a1[q] = lds_rd8(h1_lds, DECH*2, lr, 32*q+8*lg);
        f32x4 c2 = {db2v,db2v,db2v,db2v};
#pragma unroll
        for(int q=0;q<2;++q) c2 = MFMA16(a1[q], DF(4+q), c2);
        if(act){
#pragma unroll
            for(int r=0;r<4;++r) lds_wr1(h2_lds, DECH*2, row0+r, 16*wv+lr, fmaxf(c2[r],0.f));
        }
        __syncthreads();
        f16x8 a2[2];
#pragma unroll
        for(int q=0;q<2;++q) a2[q] = lds_rd8(h2_lds, DECH*2, lr, 32*q+8*lg);
#pragma unroll
        for(int u=0;u<2;++u){
            f32x4 c3 = {db3v[u],db3v[u],db3v[u],db3v[u]};
#pragma unroll
            for(int q=0;q<2;++q) c3 = MFMA16(a2[q], DF(6+2*u+q), c3);
            if(act){
#pragma unroll
                for(int r=0;r<4;++r)
                    out[(size_t)(gRow0+row0+r)*TT*OUTD + (size_t)(TT-1)*OUTD + 32*wv+16*u+lr] = c3[r];
            }
        }
    }
}

extern "C" void kernel_launch(void* const* d_in, const int* in_sizes, int n_in,
                              void* d_out, int out_size, void* d_ws, size_t ws_size,
                              hipStream_t stream) {
    ode_decoder_kernel<<<dim3(4096/ROWS), dim3(WGSZ), 0, stream>>>(
        (const float*)d_in[0],  (const float*)d_in[1],
        (const float*)d_in[2],  (const float*)d_in[3],
        (const float*)d_in[4],  (const float*)d_in[5],
        (const float*)d_in[6],  (const float*)d_in[7],
        (const float*)d_in[8],  (const float*)d_in[9],
        (const float*)d_in[10], (const float*)d_in[11],
        (float*)d_out);
}

// Round 3
// 129.954 us; speedup vs baseline: 5.1638x; 5.1638x over previous
//
#include <hip/hip_runtime.h>

#define LATENT 128
#define HIDDEN 256
#define OUTD   128
#define TT     100
#define DECH   64
#define NMACRO 25   // RK4 macro-steps of 4 grid intervals (last = 3 intervals)

typedef _Float16 f16x8 __attribute__((ext_vector_type(8)));
typedef float    f32x4 __attribute__((ext_vector_type(4)));

#define MFMA16(a,b,c) __builtin_amdgcn_mfma_f32_16x16x32_f16((a),(b),(c),0,0,0)

__device__ __forceinline__ float tanh_fast(float x){
    float e = __expf(2.f*x);                         // e^{2x}
    return 1.f - 2.f*__builtin_amdgcn_rcpf(e + 1.f); // exact limits at +-inf
}

// XOR-swizzled LDS helpers (16B-granule swizzle: b128 reads at fixed col across
// 16 rows hit all 32 banks; granule-local 2B writes are <=2-way = free)
__device__ __forceinline__ f16x8 lds_rd8(const _Float16* b, int sB, int row, int colE){
    int off = row*sB + colE*2; off ^= (row&7)<<4;
    return *(const f16x8*)((const char*)b + off);
}
__device__ __forceinline__ void lds_wr1(_Float16* b, int sB, int row, int colE, float v){
    int off = row*sB + colE*2; off ^= (row&7)<<4;
    *(_Float16*)((char*)b + off) = (_Float16)v;
}

// one-time gather of a B fragment from row-major fp32 W[K][N]:
// lane layout B[k0 + 8*(lane>>4) + i][n]
__device__ __forceinline__ f16x8 gbl_bfrag(const float* W, int ldN, int k0, int n){
    f16x8 f;
#pragma unroll
    for(int i=0;i<8;++i) f[i] = (_Float16)W[(size_t)(k0+i)*ldN + n];
    return f;
}

__global__ __launch_bounds__(512, 2) void ode_decoder_kernel(
    const float* __restrict__ z0, const float* __restrict__ times,
    const float* __restrict__ W1, const float* __restrict__ b1,
    const float* __restrict__ W2, const float* __restrict__ b2,
    const float* __restrict__ dW1, const float* __restrict__ db1,
    const float* __restrict__ dW2, const float* __restrict__ db2,
    const float* __restrict__ dW3, const float* __restrict__ db3,
    float* __restrict__ out)
{
    __shared__ _Float16 z_lds [16*LATENT] __attribute__((aligned(16))); // 4 KB
    __shared__ _Float16 h_lds [16*HIDDEN] __attribute__((aligned(16))); // 8 KB
    __shared__ _Float16 zint  [64*LATENT] __attribute__((aligned(16))); // 16 KB (4 t-pts x 16 rows)
    __shared__ _Float16 h1int [64*DECH]   __attribute__((aligned(16))); // 8 KB
    __shared__ _Float16 h2int [64*DECH]   __attribute__((aligned(16))); // 8 KB
    __shared__ float    tl[TT];

    const int tid  = threadIdx.x;
    const int wv   = tid >> 6;      // 0..7
    const int lane = tid & 63;
    const int lr   = lane & 15;
    const int lg   = lane >> 4;     // 0..3
    const int row0 = 4*lg;
    const int gRow0 = blockIdx.x * 16;
    const int nsl  = wv & 3;        // decoder n-slice for dG1/dG2
    const int mtb  = 2*(wv >> 2);   // decoder m-tile base for dG1/dG2

    if(tid < TT) tl[tid] = times[tid];

    // ---------- ODE weights pinned in VGPRs (R1 layout, verified) ----------
    f16x8 w1f[2][4];
#pragma unroll
    for(int t=0;t<2;++t)
#pragma unroll
        for(int q=0;q<4;++q)
            w1f[t][q] = gbl_bfrag(W1, HIDDEN, 32*q+8*lg, 32*wv+16*t+lr);
    f16x8 w2f[8];
#pragma unroll
    for(int q=0;q<8;++q)
        w2f[q] = gbl_bfrag(W2, LATENT, 32*q+8*lg, 16*wv+lr);

    // ---------- decoder weights in VGPRs ----------
    f16x8 dw1f[4], dw2f[2], dw3f[2];
#pragma unroll
    for(int q=0;q<4;++q) dw1f[q] = gbl_bfrag(dW1, DECH, 32*q+8*lg, 16*nsl+lr);
#pragma unroll
    for(int q=0;q<2;++q) dw2f[q] = gbl_bfrag(dW2, DECH, 32*q+8*lg, 16*nsl+lr);
#pragma unroll
    for(int q=0;q<2;++q) dw3f[q] = gbl_bfrag(dW3, OUTD, 32*q+8*lg, 16*wv+lr);

    const float b1v0 = b1[32*wv+lr], b1v1 = b1[32*wv+16+lr];
    const float b2v  = b2[16*wv+lr];
    const float db1v = db1[16*nsl+lr], db2v = db2[16*nsl+lr];
    const float db3v = db3[16*wv+lr];

    // ---------- state: lane owns z[row0+r][16*wv+lr] ----------
    f32x4 z, acc = {0,0,0,0}, zA = {0,0,0,0}, fA = {0,0,0,0};
#pragma unroll
    for(int r=0;r<4;++r) z[r] = z0[(size_t)(gRow0+row0+r)*LATENT + 16*wv + lr];
#pragma unroll
    for(int r=0;r<4;++r) lds_wr1(z_lds, LATENT*2, row0+r, 16*wv+lr, z[r]);
    __syncthreads();

    // ---------- segment bodies ----------
    auto G1SEG = [&]{   // z_lds -> h_lds = tanh(z@W1+b1)
        f16x8 az[4];
#pragma unroll
        for(int q=0;q<4;++q) az[q] = lds_rd8(z_lds, LATENT*2, lr, 32*q+8*lg);
        f32x4 c0 = {b1v0,b1v0,b1v0,b1v0};
        f32x4 c1 = {b1v1,b1v1,b1v1,b1v1};
#pragma unroll
        for(int q=0;q<4;++q){ c0 = MFMA16(az[q], w1f[0][q], c0); c1 = MFMA16(az[q], w1f[1][q], c1); }
#pragma unroll
        for(int r=0;r<4;++r){
            lds_wr1(h_lds, HIDDEN*2, row0+r, 32*wv+lr,    tanh_fast(c0[r]));
            lds_wr1(h_lds, HIDDEN*2, row0+r, 32*wv+16+lr, tanh_fast(c1[r]));
        }
    };
    auto G2SEG = [&]() -> f32x4 {   // h_lds -> kk = h@W2+b2
        f16x8 ah[8];
#pragma unroll
        for(int q=0;q<8;++q) ah[q] = lds_rd8(h_lds, HIDDEN*2, lr, 32*q+8*lg);
        f32x4 ca = {b2v,b2v,b2v,b2v}, cb = {0,0,0,0};
#pragma unroll
        for(int q=0;q<4;++q){ ca = MFMA16(ah[q], w2f[q], ca); cb = MFMA16(ah[4+q], w2f[4+q], cb); }
        return ca + cb;
    };
    auto WRZ = [&](f32x4 zs){
#pragma unroll
        for(int r=0;r<4;++r) lds_wr1(z_lds, LATENT*2, row0+r, 16*wv+lr, zs[r]);
    };
    // cubic Hermite dense output for interval [tl[base], tl[base]+hp] -> zint (4 t-pts x 16 rows)
    auto INTERP = [&](int base, float hp, f32x4 f1){
        const float rhp = 1.f/hp;
#pragma unroll
        for(int i=0;i<4;++i){
            float th = (tl[base+i]-tl[base])*rhp;
            float t2 = th*th, t3 = t2*th;
            float a0 = 2.f*t3-3.f*t2+1.f, a1 = (t3-2.f*t2+th)*hp;
            float a2 = 3.f*t2-2.f*t3,     a3 = (t3-t2)*hp;
#pragma unroll
            for(int r=0;r<4;++r){
                float v = a0*zA[r] + a1*fA[r] + a2*z[r] + a3*f1[r];
                lds_wr1(zint, LATENT*2, 16*i+row0+r, 16*wv+lr, v);
            }
        }
    };
    auto DG1 = [&]{   // zint -> h1int (wave: n-slice nsl, m-tiles mtb,mtb+1)
#pragma unroll
        for(int m=0;m<2;++m){ int mt = mtb+m;
            f32x4 c = {db1v,db1v,db1v,db1v};
#pragma unroll
            for(int q=0;q<4;++q) c = MFMA16(lds_rd8(zint, LATENT*2, 16*mt+lr, 32*q+8*lg), dw1f[q], c);
#pragma unroll
            for(int r=0;r<4;++r) lds_wr1(h1int, DECH*2, 16*mt+row0+r, 16*nsl+lr, fmaxf(c[r],0.f));
        }
    };
    auto DG2 = [&]{   // h1int -> h2int
#pragma unroll
        for(int m=0;m<2;++m){ int mt = mtb+m;
            f32x4 c = {db2v,db2v,db2v,db2v};
#pragma unroll
            for(int q=0;q<2;++q) c = MFMA16(lds_rd8(h1int, DECH*2, 16*mt+lr, 32*q+8*lg), dw2f[q], c);
#pragma unroll
            for(int r=0;r<4;++r) lds_wr1(h2int, DECH*2, 16*mt+row0+r, 16*nsl+lr, fmaxf(c[r],0.f));
        }
    };
    auto DG3 = [&](int m0d){   // h2int -> out[:, m0d..m0d+3, 16wv..16wv+15]
#pragma unroll
        for(int mt=0;mt<4;++mt){
            f32x4 c = {db3v,db3v,db3v,db3v};
#pragma unroll
            for(int q=0;q<2;++q) c = MFMA16(lds_rd8(h2int, DECH*2, 16*mt+lr, 32*q+8*lg), dw3f[q], c);
#pragma unroll
            for(int r=0;r<4;++r)
                out[(size_t)(gRow0+row0+r)*TT*OUTD + (size_t)(m0d+mt)*OUTD + 16*wv+lr] = c[r];
        }
    };

    // ---------- main: 25 RK4 macro-steps; decode interval j-1 during step j ----------
#pragma unroll 1
    for(int j=0;j<NMACRO;++j){
        const int  m0  = 4*j;
        const int  m1  = (m0+4 < TT-1) ? m0+4 : TT-1;
        const float hj = tl[m1]-tl[m0];
        const bool dec = (j>0);
        const int  dm0 = 4*(j-1);

        // stage 0
        G1SEG();
        __syncthreads();
        {
            f32x4 k1 = G2SEG();
            if(dec) INTERP(dm0, tl[m0]-tl[dm0], k1);
            zA = z; fA = k1;
            acc = z + k1*(hj*(1.f/6.f));
            WRZ(z + k1*(hj*0.5f));
        }
        __syncthreads();
        // stage 1
        G1SEG(); if(dec) DG1();
        __syncthreads();
        {
            f32x4 k2 = G2SEG(); if(dec) DG2();
            acc += k2*(hj*(1.f/3.f));
            WRZ(z + k2*(hj*0.5f));
        }
        __syncthreads();
        // stage 2
        G1SEG(); if(dec) DG3(dm0);
        __syncthreads();
        {
            f32x4 k3 = G2SEG();
            acc += k3*(hj*(1.f/3.f));
            WRZ(z + k3*hj);
        }
        __syncthreads();
        // stage 3
        G1SEG();
        __syncthreads();
        {
            f32x4 k4 = G2SEG();
            z = acc + k4*(hj*(1.f/6.f));
            WRZ(z);
        }
        __syncthreads();
    }

    // ---------- tail: f(z_end) for last interval's Hermite, then decode it ----------
    G1SEG();
    __syncthreads();
    {
        f32x4 k1 = G2SEG();
        INTERP(4*(NMACRO-1), tl[TT-1]-tl[4*(NMACRO-1)], k1);
    }
    __syncthreads();
    DG1();
    __syncthreads();
    DG2();
    __syncthreads();
    DG3(4*(NMACRO-1));
}

extern "C" void kernel_launch(void* const* d_in, const int* in_sizes, int n_in,
                              void* d_out, int out_size, void* d_ws, size_t ws_size,
                              hipStream_t stream) {
    ode_decoder_kernel<<<dim3(256), dim3(512), 0, stream>>>(
        (const float*)d_in[0],  (const float*)d_in[1],
        (const float*)d_in[2],  (const float*)d_in[3],
        (const float*)d_in[4],  (const float*)d_in[5],
        (const float*)d_in[6],  (const float*)d_in[7],
        (const float*)d_in[8],  (const float*)d_in[9],
        (const float*)d_in[10], (const float*)d_in[11],
        (float*)d_out);
}

// Round 4
// 92.436 us; speedup vs baseline: 7.2597x; 1.4059x over previous
//
#include <hip/hip_runtime.h>

#define LATENT 128
#define HIDDEN 256
#define OUTD   128
#define TT     100
#define DECH   64
#define NMACRO 13   // RK4 macro-steps of 8 grid intervals (last = 3)

typedef _Float16 f16x8 __attribute__((ext_vector_type(8)));
typedef float    f32x4 __attribute__((ext_vector_type(4)));

#define MFMA16(a,b,c) __builtin_amdgcn_mfma_f32_16x16x32_f16((a),(b),(c),0,0,0)

__device__ __forceinline__ float tanh_fast(float x){
    float e = __expf(2.f*x);
    return 1.f - 2.f*__builtin_amdgcn_rcpf(e + 1.f);
}

__device__ __forceinline__ f16x8 lds_rd8(const _Float16* b, int sB, int row, int colE){
    int off = row*sB + colE*2; off ^= (row&7)<<4;
    return *(const f16x8*)((const char*)b + off);
}
__device__ __forceinline__ void lds_wr1(_Float16* b, int sB, int row, int colE, float v){
    int off = row*sB + colE*2; off ^= (row&7)<<4;
    *(_Float16*)((char*)b + off) = (_Float16)v;
}

__device__ __forceinline__ f16x8 gbl_bfrag(const float* W, int ldN, int k0, int n){
    f16x8 f;
#pragma unroll
    for(int i=0;i<8;++i) f[i] = (_Float16)W[(size_t)(k0+i)*ldN + n];
    return f;
}

__global__ __launch_bounds__(512, 2) void ode_decoder_kernel(
    const float* __restrict__ z0, const float* __restrict__ times,
    const float* __restrict__ W1, const float* __restrict__ b1,
    const float* __restrict__ W2, const float* __restrict__ b2,
    const float* __restrict__ dW1, const float* __restrict__ db1,
    const float* __restrict__ dW2, const float* __restrict__ db2,
    const float* __restrict__ dW3, const float* __restrict__ db3,
    float* __restrict__ out)
{
    __shared__ _Float16 z_lds [16*LATENT] __attribute__((aligned(16))); // 4 KB
    __shared__ _Float16 h_lds [16*HIDDEN] __attribute__((aligned(16))); // 8 KB
    __shared__ _Float16 zint  [64*LATENT] __attribute__((aligned(16))); // 16 KB (one 4-pt round)
    __shared__ _Float16 h1int [64*DECH]   __attribute__((aligned(16))); // 8 KB
    __shared__ _Float16 h2int [64*DECH]   __attribute__((aligned(16))); // 8 KB
    __shared__ float    tl[TT];

    const int tid  = threadIdx.x;
    const int wv   = tid >> 6;
    const int lane = tid & 63;
    const int lr   = lane & 15;
    const int lg   = lane >> 4;
    const int row0 = 4*lg;
    const int gRow0 = blockIdx.x * 16;
    const int nsl  = wv & 3;
    const int mtb  = 2*(wv >> 2);

    if(tid < TT) tl[tid] = times[tid];

    // ---------- ODE weights pinned in VGPRs ----------
    f16x8 w1f[2][4];
#pragma unroll
    for(int t=0;t<2;++t)
#pragma unroll
        for(int q=0;q<4;++q)
            w1f[t][q] = gbl_bfrag(W1, HIDDEN, 32*q+8*lg, 32*wv+16*t+lr);
    f16x8 w2f[8];
#pragma unroll
    for(int q=0;q<8;++q)
        w2f[q] = gbl_bfrag(W2, LATENT, 32*q+8*lg, 16*wv+lr);

    // ---------- decoder weights in VGPRs ----------
    f16x8 dw1f[4], dw2f[2], dw3f[2];
#pragma unroll
    for(int q=0;q<4;++q) dw1f[q] = gbl_bfrag(dW1, DECH, 32*q+8*lg, 16*nsl+lr);
#pragma unroll
    for(int q=0;q<2;++q) dw2f[q] = gbl_bfrag(dW2, DECH, 32*q+8*lg, 16*nsl+lr);
#pragma unroll
    for(int q=0;q<2;++q) dw3f[q] = gbl_bfrag(dW3, OUTD, 32*q+8*lg, 16*wv+lr);

    const float b1v0 = b1[32*wv+lr], b1v1 = b1[32*wv+16+lr];
    const float b2v  = b2[16*wv+lr];
    const float db1v = db1[16*nsl+lr], db2v = db2[16*nsl+lr];
    const float db3v = db3[16*wv+lr];

    f32x4 z, acc = {0,0,0,0};
    f32x4 zA = {0,0,0,0}, fA = {0,0,0,0};          // state/deriv at previous macro start
    f32x4 izA = {0,0,0,0}, ifA = {0,0,0,0};        // Hermite endpoints of interval being decoded
    f32x4 izB = {0,0,0,0}, ifB = {0,0,0,0};
#pragma unroll
    for(int r=0;r<4;++r) z[r] = z0[(size_t)(gRow0+row0+r)*LATENT + 16*wv + lr];
#pragma unroll
    for(int r=0;r<4;++r) lds_wr1(z_lds, LATENT*2, row0+r, 16*wv+lr, z[r]);
    __syncthreads();

    auto G1SEG = [&]{
        f16x8 az[4];
#pragma unroll
        for(int q=0;q<4;++q) az[q] = lds_rd8(z_lds, LATENT*2, lr, 32*q+8*lg);
        f32x4 c0 = {b1v0,b1v0,b1v0,b1v0};
        f32x4 c1 = {b1v1,b1v1,b1v1,b1v1};
#pragma unroll
        for(int q=0;q<4;++q){ c0 = MFMA16(az[q], w1f[0][q], c0); c1 = MFMA16(az[q], w1f[1][q], c1); }
#pragma unroll
        for(int r=0;r<4;++r){
            lds_wr1(h_lds, HIDDEN*2, row0+r, 32*wv+lr,    tanh_fast(c0[r]));
            lds_wr1(h_lds, HIDDEN*2, row0+r, 32*wv+16+lr, tanh_fast(c1[r]));
        }
    };
    auto G2SEG = [&]() -> f32x4 {
        f16x8 ah[8];
#pragma unroll
        for(int q=0;q<8;++q) ah[q] = lds_rd8(h_lds, HIDDEN*2, lr, 32*q+8*lg);
        f32x4 ca = {b2v,b2v,b2v,b2v}, cb = {0,0,0,0};
#pragma unroll
        for(int q=0;q<4;++q){ ca = MFMA16(ah[q], w2f[q], ca); cb = MFMA16(ah[4+q], w2f[4+q], cb); }
        return ca + cb;
    };
    auto WRZ = [&](f32x4 zs){
#pragma unroll
        for(int r=0;r<4;++r) lds_wr1(z_lds, LATENT*2, row0+r, 16*wv+lr, zs[r]);
    };
    // Hermite dense output: 4 points basePt..basePt+3 of interval [t0, t0+hp] -> zint
    auto INTERP4 = [&](int basePt, float t0, float hp, float rhp){
#pragma unroll
        for(int i=0;i<4;++i){
            float th = (tl[basePt+i]-t0)*rhp;
            float t2 = th*th, t3 = t2*th;
            float a0 = 2.f*t3-3.f*t2+1.f, a1 = (t3-2.f*t2+th)*hp;
            float a2 = 3.f*t2-2.f*t3,     a3 = (t3-t2)*hp;
#pragma unroll
            for(int r=0;r<4;++r){
                float v = a0*izA[r] + a1*ifA[r] + a2*izB[r] + a3*ifB[r];
                lds_wr1(zint, LATENT*2, 16*i+row0+r, 16*wv+lr, v);
            }
        }
    };
    auto DG1 = [&]{
#pragma unroll
        for(int m=0;m<2;++m){ int mt = mtb+m;
            f32x4 c = {db1v,db1v,db1v,db1v};
#pragma unroll
            for(int q=0;q<4;++q) c = MFMA16(lds_rd8(zint, LATENT*2, 16*mt+lr, 32*q+8*lg), dw1f[q], c);
#pragma unroll
            for(int r=0;r<4;++r) lds_wr1(h1int, DECH*2, 16*mt+row0+r, 16*nsl+lr, fmaxf(c[r],0.f));
        }
    };
    auto DG2 = [&]{
#pragma unroll
        for(int m=0;m<2;++m){ int mt = mtb+m;
            f32x4 c = {db2v,db2v,db2v,db2v};
#pragma unroll
            for(int q=0;q<2;++q) c = MFMA16(lds_rd8(h1int, DECH*2, 16*mt+lr, 32*q+8*lg), dw2f[q], c);
#pragma unroll
            for(int r=0;r<4;++r) lds_wr1(h2int, DECH*2, 16*mt+row0+r, 16*nsl+lr, fmaxf(c[r],0.f));
        }
    };
    auto DG3 = [&](int basePt){
#pragma unroll
        for(int mt=0;mt<4;++mt){
            f32x4 c = {db3v,db3v,db3v,db3v};
#pragma unroll
            for(int q=0;q<2;++q) c = MFMA16(lds_rd8(h2int, DECH*2, 16*mt+lr, 32*q+8*lg), dw3f[q], c);
#pragma unroll
            for(int r=0;r<4;++r)
                out[(size_t)(gRow0+row0+r)*TT*OUTD + (size_t)(basePt+mt)*OUTD + 16*wv+lr] = c[r];
        }
    };

    // ---------- main: 13 macro RK4 steps (8 grid intervals each; last 3) ----------
#pragma unroll 1
    for(int j=0;j<NMACRO;++j){
        const int  m0 = 8*j;
        const int  m1 = (m0+8 < TT-1) ? m0+8 : TT-1;
        const float hj = tl[m1]-tl[m0];
        const bool dec  = (j>=1);
        const bool dec3b = (j>=2);
        const int  pA0 = 8*(j-1);          // first grid pt of interval being decoded
        const float t0  = dec ? tl[pA0] : 1.f;
        const float hp  = dec ? (tl[m0]-t0) : 1.f;
        const float rhp = 1.f/hp;

        // stage 0
        G1SEG(); if(dec3b) DG3(8*(j-2)+4);
        __syncthreads();
        {
            f32x4 k1 = G2SEG();
            if(dec){ izA = zA; ifA = fA; izB = z; ifB = k1; INTERP4(pA0, t0, hp, rhp); }
            zA = z; fA = k1;
            acc = z + k1*(hj*(1.f/6.f));
            WRZ(z + k1*(hj*0.5f));
        }
        __syncthreads();
        // stage 1
        G1SEG(); if(dec) DG1();
        __syncthreads();
        {
            f32x4 k2 = G2SEG(); if(dec) DG2();
            acc += k2*(hj*(1.f/3.f));
            WRZ(z + k2*(hj*0.5f));
        }
        __syncthreads();
        // stage 2
        G1SEG(); if(dec) DG3(pA0);
        __syncthreads();
        {
            f32x4 k3 = G2SEG();
            if(dec) INTERP4(pA0+4, t0, hp, rhp);
            acc += k3*(hj*(1.f/3.f));
            WRZ(z + k3*hj);
        }
        __syncthreads();
        // stage 3
        G1SEG(); if(dec) DG1();
        __syncthreads();
        {
            f32x4 k4 = G2SEG(); if(dec) DG2();
            z = acc + k4*(hj*(1.f/6.f));
            WRZ(z);
        }
        __syncthreads();
    }

    // ---------- tail: DG3-B of interval 11, then decode interval 12 (pts 96..99) ----------
    G1SEG(); DG3(8*(NMACRO-2)+4);
    __syncthreads();
    {
        f32x4 k1 = G2SEG();
        const int pA0 = 8*(NMACRO-1);
        const float t0 = tl[pA0], hp = tl[TT-1]-t0, rhp = 1.f/hp;
        izA = zA; ifA = fA; izB = z; ifB = k1;
        INTERP4(pA0, t0, hp, rhp);
    }
    __syncthreads();
    DG1();
    __syncthreads();
    DG2();
    __syncthreads();
    DG3(8*(NMACRO-1));
}

extern "C" void kernel_launch(void* const* d_in, const int* in_sizes, int n_in,
                              void* d_out, int out_size, void* d_ws, size_t ws_size,
                              hipStream_t stream) {
    ode_decoder_kernel<<<dim3(256), dim3(512), 0, stream>>>(
        (const float*)d_in[0],  (const float*)d_in[1],
        (const float*)d_in[2],  (const float*)d_in[3],
        (const float*)d_in[4],  (const float*)d_in[5],
        (const float*)d_in[6],  (const float*)d_in[7],
        (const float*)d_in[8],  (const float*)d_in[9],
        (const float*)d_in[10], (const float*)d_in[11],
        (float*)d_out);
}